// Round 1
// baseline (1891.673 us; speedup 1.0000x reference)
//
#include <hip/hip_runtime.h>
#include <hip/hip_bf16.h>

constexpr int N_NODES = 20000;
constexpr int N_EDGES = 320000;

// ws float layout:
//   A0  [N][64]        offset 0
//   A1O [N][64][3]     offset N*64
//   A1E [N][32][3]     offset N*256
//   A2E [N][32][5]     offset N*352
// total N*512 floats = 40.96 MB

__global__ __launch_bounds__(256) void edge_kernel(
    const float* __restrict__ pos, const float* __restrict__ x0,
    const float* __restrict__ x1, const int* __restrict__ snd,
    const int* __restrict__ rcv,
    float* __restrict__ A0, float* __restrict__ A1O,
    float* __restrict__ A1E, float* __restrict__ A2E)
{
    int tid = blockIdx.x * 256 + threadIdx.x;
    if (tid >= N_EDGES * 32) return;
    int e = tid >> 5;
    int m = tid & 31;
    int s = snd[e];
    int r = rcv[e];

    float vx = pos[r * 3 + 0] - pos[s * 3 + 0];
    float vy = pos[r * 3 + 1] - pos[s * 3 + 1];
    float vz = pos[r * 3 + 2] - pos[s * 3 + 2];
    float nrm = fmaxf(sqrtf(vx * vx + vy * vy + vz * vz), 1e-12f);
    float sc = 1.7320508075688772f / nrm;              // sqrt(3)/r
    float bx = vx * sc, by = vy * sc, bz = vz * sc;    // sh

    float s0m = x0[s * 32 + m];
    const float* s1p = x1 + (size_t)(s * 32 + m) * 3;
    float ax = s1p[0], ay = s1p[1], az = s1p[2];

    const float is2 = 0.7071067811865476f;   // 1/sqrt(2)
    const float is3 = 0.5773502691896258f;   // 1/sqrt(3)
    const float is6 = 0.4082482904638630f;   // 1/sqrt(6)

    float t0e  = (ax * bx + ay * by + az * bz) * is3;
    float t1ox = s0m * bx, t1oy = s0m * by, t1oz = s0m * bz;
    float t1ex = (ay * bz - az * by) * is2;
    float t1ey = (az * bx - ax * bz) * is2;
    float t1ez = (ax * by - ay * bx) * is2;
    float t2e0 = (ax * by + ay * bx) * is2;
    float t2e1 = (ay * bz + az * by) * is2;
    float t2e2 = (2.0f * az * bz - ax * bx - ay * by) * is6;
    float t2e3 = (ax * bz + az * bx) * is2;
    float t2e4 = (ax * bx - ay * by) * is2;

    float* a0 = A0 + (size_t)r * 64;
    unsafeAtomicAdd(a0 + m, s0m);
    unsafeAtomicAdd(a0 + 32 + m, t0e);

    float* a1o = A1O + (size_t)r * 192;
    unsafeAtomicAdd(a1o + m * 3 + 0, ax);
    unsafeAtomicAdd(a1o + m * 3 + 1, ay);
    unsafeAtomicAdd(a1o + m * 3 + 2, az);
    unsafeAtomicAdd(a1o + 96 + m * 3 + 0, t1ox);
    unsafeAtomicAdd(a1o + 96 + m * 3 + 1, t1oy);
    unsafeAtomicAdd(a1o + 96 + m * 3 + 2, t1oz);

    float* a1e = A1E + (size_t)r * 96;
    unsafeAtomicAdd(a1e + m * 3 + 0, t1ex);
    unsafeAtomicAdd(a1e + m * 3 + 1, t1ey);
    unsafeAtomicAdd(a1e + m * 3 + 2, t1ez);

    float* a2e = A2E + (size_t)r * 160;
    unsafeAtomicAdd(a2e + m * 5 + 0, t2e0);
    unsafeAtomicAdd(a2e + m * 5 + 1, t2e1);
    unsafeAtomicAdd(a2e + m * 5 + 2, t2e2);
    unsafeAtomicAdd(a2e + m * 5 + 3, t2e3);
    unsafeAtomicAdd(a2e + m * 5 + 4, t2e4);
}

__global__ __launch_bounds__(256) void node_kernel(
    const float* __restrict__ x0, const float* __restrict__ x1,
    const float* __restrict__ A0, const float* __restrict__ A1O,
    const float* __restrict__ A1E, const float* __restrict__ A2E,
    const float* __restrict__ w_sc0, const float* __restrict__ w_sc1o,
    const float* __restrict__ w_pre0, const float* __restrict__ w_pre1o,
    const float* __restrict__ w_pre1e, const float* __restrict__ w_pre2e,
    const float* __restrict__ w_post0, const float* __restrict__ w_post1o,
    const float* __restrict__ w_post1e, const float* __restrict__ w_post2e,
    float* __restrict__ out)
{
    __shared__ float sh_h0[8][32];
    __shared__ float sh_h1o[8][32][3];
    __shared__ float sh_h1e[8][32][3];
    __shared__ float sh_h2e[8][32][5];

    int local = threadIdx.x >> 5;
    int o = threadIdx.x & 31;
    int v = blockIdx.x * 8 + local;   // N_NODES = 2500*8, no tail

    const float inv   = 0.25f;                   // 1/sqrt(16)
    const float is64  = 0.125f;                  // 1/sqrt(64)
    const float is32  = 0.1767766952966369f;     // 1/sqrt(32)

    // ---- h0 = gelu(lin(a0, w_pre0)) ----
    const float* a0 = A0 + (size_t)v * 64;
    float acc = 0.f;
    #pragma unroll 8
    for (int m = 0; m < 64; ++m) acc += a0[m] * w_pre0[m * 32 + o];
    acc *= inv * is64;
    {
        float x3 = acc * acc * acc;
        float t = tanhf(0.7978845608028654f * (acc + 0.044715f * x3));
        sh_h0[local][o] = 0.5f * acc * (1.f + t);
    }

    // ---- h1o = lin(a1o, w_pre1o) ----
    {
        const float* a1o = A1O + (size_t)v * 192;
        float c0 = 0.f, c1 = 0.f, c2 = 0.f;
        #pragma unroll 8
        for (int m = 0; m < 64; ++m) {
            float w = w_pre1o[m * 32 + o];
            c0 += a1o[m * 3 + 0] * w;
            c1 += a1o[m * 3 + 1] * w;
            c2 += a1o[m * 3 + 2] * w;
        }
        float s = inv * is64;
        sh_h1o[local][o][0] = c0 * s;
        sh_h1o[local][o][1] = c1 * s;
        sh_h1o[local][o][2] = c2 * s;
    }

    // ---- h1e = lin(a1e, w_pre1e) ----
    {
        const float* a1e = A1E + (size_t)v * 96;
        float c0 = 0.f, c1 = 0.f, c2 = 0.f;
        #pragma unroll 8
        for (int m = 0; m < 32; ++m) {
            float w = w_pre1e[m * 32 + o];
            c0 += a1e[m * 3 + 0] * w;
            c1 += a1e[m * 3 + 1] * w;
            c2 += a1e[m * 3 + 2] * w;
        }
        float s = inv * is32;
        sh_h1e[local][o][0] = c0 * s;
        sh_h1e[local][o][1] = c1 * s;
        sh_h1e[local][o][2] = c2 * s;
    }

    // ---- h2e = lin(a2e, w_pre2e) ----
    {
        const float* a2e = A2E + (size_t)v * 160;
        float c0 = 0.f, c1 = 0.f, c2 = 0.f, c3 = 0.f, c4 = 0.f;
        #pragma unroll 8
        for (int m = 0; m < 32; ++m) {
            float w = w_pre2e[m * 32 + o];
            c0 += a2e[m * 5 + 0] * w;
            c1 += a2e[m * 5 + 1] * w;
            c2 += a2e[m * 5 + 2] * w;
            c3 += a2e[m * 5 + 3] * w;
            c4 += a2e[m * 5 + 4] * w;
        }
        float s = inv * is32;
        sh_h2e[local][o][0] = c0 * s;
        sh_h2e[local][o][1] = c1 * s;
        sh_h2e[local][o][2] = c2 * s;
        sh_h2e[local][o][3] = c3 * s;
        sh_h2e[local][o][4] = c4 * s;
    }

    __syncthreads();

    float* orow = out + (size_t)v * 384;

    // ---- y0 = lin(x0,w_sc0) + lin(h0,w_post0) ----
    {
        const float* x0v = x0 + (size_t)v * 32;
        float c = 0.f;
        #pragma unroll 8
        for (int m = 0; m < 32; ++m) {
            c += x0v[m] * w_sc0[m * 32 + o];
            c += sh_h0[local][m] * w_post0[m * 32 + o];
        }
        orow[o] = c * is32;
    }

    // ---- y1o = lin(x1,w_sc1o) + lin(h1o,w_post1o) ----
    {
        const float* x1v = x1 + (size_t)v * 96;
        float c0 = 0.f, c1 = 0.f, c2 = 0.f;
        #pragma unroll 8
        for (int m = 0; m < 32; ++m) {
            float wsc = w_sc1o[m * 32 + o];
            float wp  = w_post1o[m * 32 + o];
            c0 += x1v[m * 3 + 0] * wsc + sh_h1o[local][m][0] * wp;
            c1 += x1v[m * 3 + 1] * wsc + sh_h1o[local][m][1] * wp;
            c2 += x1v[m * 3 + 2] * wsc + sh_h1o[local][m][2] * wp;
        }
        orow[32 + o * 3 + 0] = c0 * is32;
        orow[32 + o * 3 + 1] = c1 * is32;
        orow[32 + o * 3 + 2] = c2 * is32;
    }

    // ---- y1e = lin(h1e, w_post1e) ----
    {
        float c0 = 0.f, c1 = 0.f, c2 = 0.f;
        #pragma unroll 8
        for (int m = 0; m < 32; ++m) {
            float w = w_post1e[m * 32 + o];
            c0 += sh_h1e[local][m][0] * w;
            c1 += sh_h1e[local][m][1] * w;
            c2 += sh_h1e[local][m][2] * w;
        }
        orow[128 + o * 3 + 0] = c0 * is32;
        orow[128 + o * 3 + 1] = c1 * is32;
        orow[128 + o * 3 + 2] = c2 * is32;
    }

    // ---- y2e = lin(h2e, w_post2e) ----
    {
        float c0 = 0.f, c1 = 0.f, c2 = 0.f, c3 = 0.f, c4 = 0.f;
        #pragma unroll 8
        for (int m = 0; m < 32; ++m) {
            float w = w_post2e[m * 32 + o];
            c0 += sh_h2e[local][m][0] * w;
            c1 += sh_h2e[local][m][1] * w;
            c2 += sh_h2e[local][m][2] * w;
            c3 += sh_h2e[local][m][3] * w;
            c4 += sh_h2e[local][m][4] * w;
        }
        orow[224 + o * 5 + 0] = c0 * is32;
        orow[224 + o * 5 + 1] = c1 * is32;
        orow[224 + o * 5 + 2] = c2 * is32;
        orow[224 + o * 5 + 3] = c3 * is32;
        orow[224 + o * 5 + 4] = c4 * is32;
    }
}

extern "C" void kernel_launch(void* const* d_in, const int* in_sizes, int n_in,
                              void* d_out, int out_size, void* d_ws, size_t ws_size,
                              hipStream_t stream) {
    const float* pos      = (const float*)d_in[0];
    const float* x0       = (const float*)d_in[1];
    const float* x1       = (const float*)d_in[2];
    const int*   snd      = (const int*)d_in[3];
    const int*   rcv      = (const int*)d_in[4];
    const float* w_sc0    = (const float*)d_in[5];
    const float* w_sc1o   = (const float*)d_in[6];
    const float* w_pre0   = (const float*)d_in[7];
    const float* w_pre1o  = (const float*)d_in[8];
    const float* w_pre1e  = (const float*)d_in[9];
    const float* w_pre2e  = (const float*)d_in[10];
    const float* w_post0  = (const float*)d_in[11];
    const float* w_post1o = (const float*)d_in[12];
    const float* w_post1e = (const float*)d_in[13];
    const float* w_post2e = (const float*)d_in[14];
    float* out = (float*)d_out;

    float* ws  = (float*)d_ws;
    float* A0  = ws;
    float* A1O = ws + (size_t)N_NODES * 64;
    float* A1E = ws + (size_t)N_NODES * 256;
    float* A2E = ws + (size_t)N_NODES * 352;

    hipMemsetAsync(d_ws, 0, (size_t)N_NODES * 512 * sizeof(float), stream);

    int edge_threads = N_EDGES * 32;
    edge_kernel<<<edge_threads / 256, 256, 0, stream>>>(
        pos, x0, x1, snd, rcv, A0, A1O, A1E, A2E);

    node_kernel<<<N_NODES / 8, 256, 0, stream>>>(
        x0, x1, A0, A1O, A1E, A2E,
        w_sc0, w_sc1o, w_pre0, w_pre1o, w_pre1e, w_pre2e,
        w_post0, w_post1o, w_post1e, w_post2e, out);
}

// Round 2
// 181.271 us; speedup vs baseline: 10.4356x; 10.4356x over previous
//
#include <hip/hip_runtime.h>
#include <hip/hip_bf16.h>

constexpr int N_NODES = 20000;
constexpr int N_EDGES = 320000;

// ws layout (ints):
//   offsets [N_NODES+1]
//   work    [N_NODES]      (counts, then running scatter cursor)
//   csr     [N_EDGES]      (edge ids sorted by receiver)

__global__ __launch_bounds__(256) void count_kernel(
    const int* __restrict__ rcv, int* __restrict__ work)
{
    int e = blockIdx.x * 256 + threadIdx.x;
    if (e < N_EDGES) atomicAdd(&work[rcv[e]], 1);
}

__global__ __launch_bounds__(1024) void scan_kernel(
    int* __restrict__ work, int* __restrict__ offsets)
{
    __shared__ int lds[1024];
    int tid = threadIdx.x;
    constexpr int CH = (N_NODES + 1023) / 1024;  // 20
    int base = tid * CH;

    int s = 0;
    #pragma unroll
    for (int i = 0; i < CH; ++i) {
        int idx = base + i;
        if (idx < N_NODES) s += work[idx];
    }
    lds[tid] = s;
    __syncthreads();
    for (int off = 1; off < 1024; off <<= 1) {
        int v = (tid >= off) ? lds[tid - off] : 0;
        __syncthreads();
        lds[tid] += v;
        __syncthreads();
    }
    int run = (tid == 0) ? 0 : lds[tid - 1];
    if (tid == 1023) offsets[N_NODES] = lds[1023];
    #pragma unroll
    for (int i = 0; i < CH; ++i) {
        int idx = base + i;
        if (idx < N_NODES) {
            int c = work[idx];
            offsets[idx] = run;
            work[idx] = run;   // scatter cursor
            run += c;
        }
    }
}

__global__ __launch_bounds__(256) void scatter_kernel(
    const int* __restrict__ rcv, int* __restrict__ work, int* __restrict__ csr)
{
    int e = blockIdx.x * 256 + threadIdx.x;
    if (e < N_EDGES) {
        int p = atomicAdd(&work[rcv[e]], 1);
        csr[p] = e;
    }
}

__global__ __launch_bounds__(256) void fused_kernel(
    const float* __restrict__ pos, const float* __restrict__ x0,
    const float* __restrict__ x1, const int* __restrict__ snd,
    const int* __restrict__ offsets, const int* __restrict__ csr,
    const float* __restrict__ w_sc0, const float* __restrict__ w_sc1o,
    const float* __restrict__ w_pre0, const float* __restrict__ w_pre1o,
    const float* __restrict__ w_pre1e, const float* __restrict__ w_pre2e,
    const float* __restrict__ w_post0, const float* __restrict__ w_post1o,
    const float* __restrict__ w_post1e, const float* __restrict__ w_post2e,
    float* __restrict__ out)
{
    __shared__ float sA0[8][64];
    __shared__ float sA1O[8][64][3];
    __shared__ float sA1E[8][32][3];
    __shared__ float sA2E[8][32][5];

    int local = threadIdx.x >> 5;
    int m = threadIdx.x & 31;
    int v = blockIdx.x * 8 + local;   // 20000 = 2500*8

    float prx = pos[v * 3 + 0], pry = pos[v * 3 + 1], prz = pos[v * 3 + 2];
    int beg = offsets[v], end = offsets[v + 1];

    const float is2 = 0.7071067811865476f;
    const float is3 = 0.5773502691896258f;
    const float is6 = 0.4082482904638630f;

    float c_s0 = 0.f, c_t0e = 0.f;
    float c_s1x = 0.f, c_s1y = 0.f, c_s1z = 0.f;
    float c_t1ox = 0.f, c_t1oy = 0.f, c_t1oz = 0.f;
    float c_t1ex = 0.f, c_t1ey = 0.f, c_t1ez = 0.f;
    float c_t2e0 = 0.f, c_t2e1 = 0.f, c_t2e2 = 0.f, c_t2e3 = 0.f, c_t2e4 = 0.f;

    for (int i = beg; i < end; ++i) {
        int e = csr[i];
        int s = snd[e];
        float vx = prx - pos[s * 3 + 0];
        float vy = pry - pos[s * 3 + 1];
        float vz = prz - pos[s * 3 + 2];
        float nrm = fmaxf(sqrtf(vx * vx + vy * vy + vz * vz), 1e-12f);
        float sc = 1.7320508075688772f / nrm;
        float bx = vx * sc, by = vy * sc, bz = vz * sc;

        float s0m = x0[s * 32 + m];
        const float* p1 = x1 + (size_t)(s * 32 + m) * 3;
        float ax = p1[0], ay = p1[1], az = p1[2];

        c_s0 += s0m;
        c_t0e += (ax * bx + ay * by + az * bz) * is3;
        c_s1x += ax; c_s1y += ay; c_s1z += az;
        c_t1ox += s0m * bx; c_t1oy += s0m * by; c_t1oz += s0m * bz;
        c_t1ex += (ay * bz - az * by) * is2;
        c_t1ey += (az * bx - ax * bz) * is2;
        c_t1ez += (ax * by - ay * bx) * is2;
        c_t2e0 += (ax * by + ay * bx) * is2;
        c_t2e1 += (ay * bz + az * by) * is2;
        c_t2e2 += (2.0f * az * bz - ax * bx - ay * by) * is6;
        c_t2e3 += (ax * bz + az * bx) * is2;
        c_t2e4 += (ax * bx - ay * by) * is2;
    }

    sA0[local][m] = c_s0;
    sA0[local][32 + m] = c_t0e;
    sA1O[local][m][0] = c_s1x;
    sA1O[local][m][1] = c_s1y;
    sA1O[local][m][2] = c_s1z;
    sA1O[local][32 + m][0] = c_t1ox;
    sA1O[local][32 + m][1] = c_t1oy;
    sA1O[local][32 + m][2] = c_t1oz;
    sA1E[local][m][0] = c_t1ex;
    sA1E[local][m][1] = c_t1ey;
    sA1E[local][m][2] = c_t1ez;
    sA2E[local][m][0] = c_t2e0;
    sA2E[local][m][1] = c_t2e1;
    sA2E[local][m][2] = c_t2e2;
    sA2E[local][m][3] = c_t2e3;
    sA2E[local][m][4] = c_t2e4;

    __syncthreads();

    const float inv  = 0.25f;                 // 1/sqrt(16)
    const float is64 = 0.125f;                // 1/sqrt(64)
    const float is32 = 0.1767766952966369f;   // 1/sqrt(32)
    int o = m;

    // ---- h intermediates (registers) ----
    float h0;
    {
        float acc = 0.f;
        #pragma unroll 8
        for (int mm = 0; mm < 64; ++mm) acc += sA0[local][mm] * w_pre0[mm * 32 + o];
        acc *= inv * is64;
        float x3 = acc * acc * acc;
        float t = tanhf(0.7978845608028654f * (acc + 0.044715f * x3));
        h0 = 0.5f * acc * (1.f + t);
    }
    float h1o0, h1o1, h1o2;
    {
        float c0 = 0.f, c1 = 0.f, c2 = 0.f;
        #pragma unroll 8
        for (int mm = 0; mm < 64; ++mm) {
            float w = w_pre1o[mm * 32 + o];
            c0 += sA1O[local][mm][0] * w;
            c1 += sA1O[local][mm][1] * w;
            c2 += sA1O[local][mm][2] * w;
        }
        float sgl = inv * is64;
        h1o0 = c0 * sgl; h1o1 = c1 * sgl; h1o2 = c2 * sgl;
    }
    float h1e0, h1e1, h1e2;
    {
        float c0 = 0.f, c1 = 0.f, c2 = 0.f;
        #pragma unroll 8
        for (int mm = 0; mm < 32; ++mm) {
            float w = w_pre1e[mm * 32 + o];
            c0 += sA1E[local][mm][0] * w;
            c1 += sA1E[local][mm][1] * w;
            c2 += sA1E[local][mm][2] * w;
        }
        float sgl = inv * is32;
        h1e0 = c0 * sgl; h1e1 = c1 * sgl; h1e2 = c2 * sgl;
    }
    float h2e0, h2e1, h2e2, h2e3, h2e4;
    {
        float c0 = 0.f, c1 = 0.f, c2 = 0.f, c3 = 0.f, c4 = 0.f;
        #pragma unroll 8
        for (int mm = 0; mm < 32; ++mm) {
            float w = w_pre2e[mm * 32 + o];
            c0 += sA2E[local][mm][0] * w;
            c1 += sA2E[local][mm][1] * w;
            c2 += sA2E[local][mm][2] * w;
            c3 += sA2E[local][mm][3] * w;
            c4 += sA2E[local][mm][4] * w;
        }
        float sgl = inv * is32;
        h2e0 = c0 * sgl; h2e1 = c1 * sgl; h2e2 = c2 * sgl;
        h2e3 = c3 * sgl; h2e4 = c4 * sgl;
    }

    // share h through LDS for the post/sc linears
    __syncthreads();
    sA0[local][o] = h0;
    sA1O[local][o][0] = h1o0; sA1O[local][o][1] = h1o1; sA1O[local][o][2] = h1o2;
    sA1E[local][o][0] = h1e0; sA1E[local][o][1] = h1e1; sA1E[local][o][2] = h1e2;
    sA2E[local][o][0] = h2e0; sA2E[local][o][1] = h2e1; sA2E[local][o][2] = h2e2;
    sA2E[local][o][3] = h2e3; sA2E[local][o][4] = h2e4;
    __syncthreads();

    float* orow = out + (size_t)v * 384;

    {
        const float* x0v = x0 + (size_t)v * 32;
        float c = 0.f;
        #pragma unroll 8
        for (int mm = 0; mm < 32; ++mm) {
            c += x0v[mm] * w_sc0[mm * 32 + o];
            c += sA0[local][mm] * w_post0[mm * 32 + o];
        }
        orow[o] = c * is32;
    }
    {
        const float* x1v = x1 + (size_t)v * 96;
        float c0 = 0.f, c1 = 0.f, c2 = 0.f;
        #pragma unroll 8
        for (int mm = 0; mm < 32; ++mm) {
            float wsc = w_sc1o[mm * 32 + o];
            float wp  = w_post1o[mm * 32 + o];
            c0 += x1v[mm * 3 + 0] * wsc + sA1O[local][mm][0] * wp;
            c1 += x1v[mm * 3 + 1] * wsc + sA1O[local][mm][1] * wp;
            c2 += x1v[mm * 3 + 2] * wsc + sA1O[local][mm][2] * wp;
        }
        orow[32 + o * 3 + 0] = c0 * is32;
        orow[32 + o * 3 + 1] = c1 * is32;
        orow[32 + o * 3 + 2] = c2 * is32;
    }
    {
        float c0 = 0.f, c1 = 0.f, c2 = 0.f;
        #pragma unroll 8
        for (int mm = 0; mm < 32; ++mm) {
            float w = w_post1e[mm * 32 + o];
            c0 += sA1E[local][mm][0] * w;
            c1 += sA1E[local][mm][1] * w;
            c2 += sA1E[local][mm][2] * w;
        }
        orow[128 + o * 3 + 0] = c0 * is32;
        orow[128 + o * 3 + 1] = c1 * is32;
        orow[128 + o * 3 + 2] = c2 * is32;
    }
    {
        float c0 = 0.f, c1 = 0.f, c2 = 0.f, c3 = 0.f, c4 = 0.f;
        #pragma unroll 8
        for (int mm = 0; mm < 32; ++mm) {
            float w = w_post2e[mm * 32 + o];
            c0 += sA2E[local][mm][0] * w;
            c1 += sA2E[local][mm][1] * w;
            c2 += sA2E[local][mm][2] * w;
            c3 += sA2E[local][mm][3] * w;
            c4 += sA2E[local][mm][4] * w;
        }
        orow[224 + o * 5 + 0] = c0 * is32;
        orow[224 + o * 5 + 1] = c1 * is32;
        orow[224 + o * 5 + 2] = c2 * is32;
        orow[224 + o * 5 + 3] = c3 * is32;
        orow[224 + o * 5 + 4] = c4 * is32;
    }
}

extern "C" void kernel_launch(void* const* d_in, const int* in_sizes, int n_in,
                              void* d_out, int out_size, void* d_ws, size_t ws_size,
                              hipStream_t stream) {
    const float* pos      = (const float*)d_in[0];
    const float* x0       = (const float*)d_in[1];
    const float* x1       = (const float*)d_in[2];
    const int*   snd      = (const int*)d_in[3];
    const int*   rcv      = (const int*)d_in[4];
    const float* w_sc0    = (const float*)d_in[5];
    const float* w_sc1o   = (const float*)d_in[6];
    const float* w_pre0   = (const float*)d_in[7];
    const float* w_pre1o  = (const float*)d_in[8];
    const float* w_pre1e  = (const float*)d_in[9];
    const float* w_pre2e  = (const float*)d_in[10];
    const float* w_post0  = (const float*)d_in[11];
    const float* w_post1o = (const float*)d_in[12];
    const float* w_post1e = (const float*)d_in[13];
    const float* w_post2e = (const float*)d_in[14];
    float* out = (float*)d_out;

    int* offsets = (int*)d_ws;              // N_NODES+1
    int* work    = offsets + N_NODES + 1;   // N_NODES
    int* csr     = work + N_NODES;          // N_EDGES

    hipMemsetAsync(work, 0, N_NODES * sizeof(int), stream);
    count_kernel<<<(N_EDGES + 255) / 256, 256, 0, stream>>>(rcv, work);
    scan_kernel<<<1, 1024, 0, stream>>>(work, offsets);
    scatter_kernel<<<(N_EDGES + 255) / 256, 256, 0, stream>>>(rcv, work, csr);

    fused_kernel<<<N_NODES / 8, 256, 0, stream>>>(
        pos, x0, x1, snd, offsets, csr,
        w_sc0, w_sc1o, w_pre0, w_pre1o, w_pre1e, w_pre2e,
        w_post0, w_post1o, w_post1e, w_post2e, out);
}